// Round 6
// baseline (10246.805 us; speedup 1.0000x reference)
//
#include <hip/hip_runtime.h>
#include <stdint.h>

typedef __attribute__((ext_vector_type(4))) float f32x4;
typedef __attribute__((ext_vector_type(2))) unsigned int u32x2;
typedef __attribute__((ext_vector_type(4))) unsigned int u32x4;

#define T_STEPS 4096
#define HID 1024
#define NBLK 256
#define NREP 16         // mailbox replicas (fan-in 256 -> 16 reader-blocks/line)

static __device__ __forceinline__ float u2f(unsigned int u) {
    union { float f; unsigned int i; } c; c.i = u; return c.f;
}
static __device__ __forceinline__ unsigned int f2u(float f) {
    union { float f; unsigned int i; } c; c.f = f; return c.i;
}

// ---------------------------------------------------------------------------
// Fully fused persistent LSTM, fp32. 256 blocks x 256 threads, 1 block/CU.
// Block b owns hidden units [4b,4b+4) -> 16 gate columns
//   col(c) = (c>>2)*1024 + b*4 + (c&3), c = tid&15.
// Thread (c, s=tid>>4) holds U/W[64s..64s+64)[col] in VGPRs.
//
// SINGLE-HOP mailbox, 16x REPLICATED. Each h value is an 8-byte pair
// {f32 h, u32 tag=t+1}, stored with ONE global_store_dwordx2 sc0 sc1
// (8 B aligned => single-copy atomic; tag arrival == data arrival).
//
// R6 vs R5 (9.45 ms, 8 replicas): replicas 8 -> 16. Publisher wave0's
// 64 lanes all store now (lane l -> replica l>>2, unit b*4+(l&3)) — still
// ONE store instruction, just a full exec mask; zero publisher-path cost.
// Readers poll replica (bid & 15): per-64B-line fan-in halves 32 -> 16
// reader-blocks. R5 confirmed fan-in congestion is the dominant step-time
// term (8x replicas = -12%); this is the last free doubling.
//
// Parity-2 slot safety (per replica, reader-subset-invariant): block b
// overwrites pair[r][p][j] (h_t -> h_{t+2}) at step t+2 only after its
// poll of ALL h_{t+1} tags succeeded; any block publishes h_{t+1} only
// after consuming h_t. Tags monotonic per slot; poll uses >=.
// Workspace: 16*2*1024 u64 = 256 KB, zeroed.
//
// Poll discipline (R1/R3 lesson): issue + s_waitcnt vmcnt(0) + check live
// in ONE asm block; nothing is in flight when the loop exits. No split
// register lifetimes across asm blocks, ever.
//
// out rows 0..4094: written by rotating block (t & 255) as one coalesced
// 4 KB row straight from poll registers. Row 4095 + h_T + c_T: per-block
// lanes 0-3 at the final step.
// ---------------------------------------------------------------------------
__global__ __launch_bounds__(256, 1) void lstm_fused(
    const float* __restrict__ x,    // [4096,1024]
    const float* __restrict__ W,    // [1024,4096]
    const float* __restrict__ U,    // [1024,4096]
    const float* __restrict__ bias, // [4096]
    float* __restrict__ out,        // [4096*1024 + 1024 + 1024]
    unsigned long long* __restrict__ pairs) // [16][2][1024] {f32,u32}, zeroed
{
    const int tid  = threadIdx.x;
    const int b    = blockIdx.x;
    const int c    = tid & 15;
    const int s    = tid >> 4;
    const int col  = (c >> 2) * 1024 + b * 4 + (c & 3);
    const int lane = tid & 63;
    const int wave = tid >> 6;

    __shared__ __align__(16) float h_lds[16 * 68];     // h[k] at (k>>6)*68+(k&63)
    __shared__ __align__(16) float x_lds[2][16 * 68];
    __shared__ __align__(16) float red[64];
    __shared__ __align__(16) float bias_l[16];

    float Ureg[64], Wreg[64];
    #pragma unroll
    for (int i = 0; i < 64; ++i) {
        const size_t r = (size_t)(s * 64 + i) * 4096 + col;
        Ureg[i] = U[r];
        Wreg[i] = W[r];
    }
    if (tid < 16) bias_l[tid] = bias[col];

    for (int i = tid; i < 16 * 68; i += 256) h_lds[i] = 0.0f;   // h0 = 0
    const int xofs = (tid >> 4) * 68 + (tid & 15) * 4;
    *(f32x4*)&x_lds[0][xofs] = *(const f32x4*)(x + (size_t)tid * 4);
    f32x4 xpre = *(const f32x4*)(x + 1024 + (size_t)tid * 4);
    __syncthreads();

    const int hbase = s * 68;
    const int hofs  = ((tid * 4) >> 6) * 68 + ((tid * 4) & 63);  // stage slot

    // prologue: W.x_0 partial (4 independent FMA chains)
    float acc_x;
    {
        float b0 = 0.f, b1 = 0.f, b2 = 0.f, b3 = 0.f;
        #pragma unroll
        for (int i = 0; i < 16; ++i) {
            f32x4 x4 = *(const f32x4*)&x_lds[0][hbase + 4 * i];
            b0 += x4.x * Wreg[4*i];   b1 += x4.y * Wreg[4*i+1];
            b2 += x4.z * Wreg[4*i+2]; b3 += x4.w * Wreg[4*i+3];
        }
        acc_x = (b0 + b1) + (b2 + b3);
    }

    float c_reg = 0.0f;   // cell state: wave-0 lane u tracks unit b*4+(u&3)

    for (int t = 0; t < T_STEPS; ++t) {
        const int p   = t & 1;
        const int nxt = (t + 1) & 1;

        // 1: acc = W.x_t (precomputed) + U.h_{t-1}
        float acc;
        {
            float a0 = 0.f, a1 = 0.f, a2 = 0.f, a3 = 0.f;
            #pragma unroll
            for (int i = 0; i < 16; ++i) {
                f32x4 h4 = *(const f32x4*)&h_lds[hbase + 4 * i];
                a0 += h4.x * Ureg[4*i];   a1 += h4.y * Ureg[4*i+1];
                a2 += h4.z * Ureg[4*i+2]; a3 += h4.w * Ureg[4*i+3];
            }
            acc = acc_x + ((a0 + a1) + (a2 + a3));
        }
        // 2: lanes {c, c+16, c+32, c+48} share a column
        acc += __shfl_down(acc, 32);
        acc += __shfl_down(acc, 16);
        if (lane < 16) red[wave * 16 + lane] = acc;

        // rotate x double-buffer: write x_{t+1}, prefetch x_{t+2}
        *(f32x4*)&x_lds[nxt][xofs] = xpre;
        {
            const int tp2 = (t + 2 < T_STEPS) ? (t + 2) : (T_STEPS - 1);
            xpre = *(const f32x4*)(x + (size_t)tp2 * 1024 + tid * 4);
        }
        __syncthreads();   // [S1] red + x_lds[nxt] visible

        // 3: wave 0 — gates; ALL 64 lanes publish {h, t+1} pairs, lane l ->
        //    unit b*4+(l&3) in replica l>>2 (one store instruction total)
        if (wave == 0) {
            const int cc = lane & 15;
            const float gv = red[cc] + red[16 + cc] + red[32 + cc] + red[48 + cc]
                           + bias_l[cc];
            const int u = lane & 3;
            const float gi = __shfl(gv, u);
            const float gf = __shfl(gv, 4 + u);
            const float gg = __shfl(gv, 8 + u);
            const float go = __shfl(gv, 12 + u);
            const float iv = 1.0f / (1.0f + __expf(-gi));
            const float fv = 1.0f / (1.0f + __expf(-gf));
            const float tg = 1.0f - 2.0f / (1.0f + __expf(2.0f * gg));
            const float ov = 1.0f / (1.0f + __expf(-go));
            const float cn = fv * c_reg + iv * tg;
            c_reg = cn;
            const float hn = ov * (1.0f - 2.0f / (1.0f + __expf(2.0f * cn)));
            if (t == T_STEPS - 1) {
                if (lane < 4) {
                    out[(size_t)t * HID + b * 4 + lane] = hn;               // row 4095
                    out[(size_t)T_STEPS * HID + b * 4 + lane] = hn;         // h_T
                    out[(size_t)T_STEPS * HID + HID + b * 4 + lane] = cn;   // c_T
                }
            } else {
                u32x2 pr;
                pr.x = f2u(hn);
                pr.y = (unsigned int)(t + 1);
                const int rep = lane >> 2;   // replica 0..15
                unsigned long long* pp = pairs + (size_t)rep * 2048
                                       + (size_t)p * 1024 + b * 4 + u;
                asm volatile("global_store_dwordx2 %0, %1, off sc0 sc1"
                             :: "v"(pp), "v"(pr) : "memory");
            }
        }
        if (t == T_STEPS - 1) break;

        // 4: all threads — W.x_{t+1} (local work first, then wait)
        {
            float b0 = 0.f, b1 = 0.f, b2 = 0.f, b3 = 0.f;
            #pragma unroll
            for (int i = 0; i < 16; ++i) {
                f32x4 x4 = *(const f32x4*)&x_lds[nxt][hbase + 4 * i];
                b0 += x4.x * Wreg[4*i];   b1 += x4.y * Wreg[4*i+1];
                b2 += x4.z * Wreg[4*i+2]; b3 += x4.w * Wreg[4*i+3];
            }
            acc_x = (b0 + b1) + (b2 + b3);
        }

        // 5: every thread polls its 4 pairs from replica (b & 15).
        //    ONE asm block per attempt (issue + vmcnt(0) + check), nothing
        //    in flight at exit.
        {
            const unsigned int want = (unsigned int)(t + 1);
            const unsigned long long* pp = pairs + (size_t)(b & 15) * 2048
                                         + (size_t)p * 1024 + tid * 4;
            u32x4 q0, q1;
            for (;;) {
                asm volatile("global_load_dwordx4 %0, %2, off sc0 sc1\n\t"
                             "global_load_dwordx4 %1, %3, off sc0 sc1\n\t"
                             "s_waitcnt vmcnt(0)"
                             : "=&v"(q0), "=&v"(q1)
                             : "v"(pp), "v"(pp + 2) : "memory");
                if (q0.y >= want && q0.w >= want && q1.y >= want && q1.w >= want)
                    break;
            }
            f32x4 hv4;
            hv4.x = u2f(q0.x); hv4.y = u2f(q0.z);
            hv4.z = u2f(q1.x); hv4.w = u2f(q1.z);
            // rotating writer: block (t & 255) emits the full coalesced row t
            if (b == (t & 255))
                *(f32x4*)(out + (size_t)t * HID + tid * 4) = hv4;
            *(f32x4*)&h_lds[hofs] = hv4;   // stage h_t
        }
        __syncthreads();   // [S2] h_t staged
    }
}

extern "C" void kernel_launch(void* const* d_in, const int* in_sizes, int n_in,
                              void* d_out, int out_size, void* d_ws, size_t ws_size,
                              hipStream_t stream) {
    const float* x    = (const float*)d_in[0];
    const float* W    = (const float*)d_in[1];
    const float* U    = (const float*)d_in[2];
    const float* bias = (const float*)d_in[3];
    float* out = (float*)d_out;

    // Workspace: pairs[16][2][1024] x 8 B = 256 KB @ +0 (zeroed: tag fields
    // must start below 1; re-poisoned 0xAA would read as huge tags).
    unsigned long long* pairs = (unsigned long long*)d_ws;

    hipMemsetAsync(pairs, 0, (size_t)NREP * 2 * 1024 * sizeof(unsigned long long), stream);
    lstm_fused<<<NBLK, 256, 0, stream>>>(x, W, U, bias, out, pairs);
}

// Round 7
// 7175.510 us; speedup vs baseline: 1.4280x; 1.4280x over previous
//
#include <hip/hip_runtime.h>
#include <stdint.h>

typedef __attribute__((ext_vector_type(4))) float f32x4;
typedef __attribute__((ext_vector_type(2))) unsigned int u32x2;
typedef __attribute__((ext_vector_type(4))) unsigned int u32x4;

#define T_STEPS 4096
#define HID 1024
#define NBLK 256
#define NREP 8          // mailbox replicas (R5-proven knee; 16 regressed)

static __device__ __forceinline__ float u2f(unsigned int u) {
    union { float f; unsigned int i; } c; c.i = u; return c.f;
}
static __device__ __forceinline__ unsigned int f2u(float f) {
    union { float f; unsigned int i; } c; c.f = f; return c.i;
}

// ---------------------------------------------------------------------------
// Fully fused persistent LSTM, fp32. 256 blocks x 256 threads, 1 block/CU.
//
// R7 restructure vs R5 (9.45 ms): PER-WAVE UNITS + INTRA-WAVE REDUCE.
// Wave w of block b owns hidden unit (b*4+w) = all 4 gate columns
//   col(g) = g*1024 + b*4 + w.  Lane l: g = l&3, seg = l>>2;
//   thread holds U/W[64*seg .. +64)[col(g)] in VGPRs (64 each, as before).
// Cross-column reduction is now 4x shfl_xor (strides 4,8,16,32) + 4 lane
// broadcasts — the red[] LDS round-trip AND the S1 barrier are GONE.
// One barrier per step (S2). All 4 waves compute gates & publish their own
// unit in parallel: lanes 0-7 -> 8 replicas (32 stores/block, identical
// mailbox traffic to R5; publish & poll phases shift together, avoiding the
// R2/R4 early-sampling congestion poison).
//
// SINGLE-HOP mailbox, 8x replicated (R5 knee; 16 replicas regressed 13%).
// Pair {f32 h, u32 tag=t+1}, one global_store_dwordx2 sc0 sc1 per lane.
// Poll: ONE asm block per round (issue + vmcnt(0) + check) — R1/R3 proved
// split-asm register lifetimes corrupt data; nothing in flight at exit.
//
// Buffering (S1 removed => cross-wave LDS needs parity separation):
//  * h_lds[2][.]: A(t) reads h_t from h_lds[p]; H(t) stages h_{t+1} into
//    h_lds[nxt]. Disjoint within an iter; S2 covers cross-iter.
//  * x_lds[2][.]: F(t) reads x_{t+1} from x_lds[nxt] (staged at E(t-1),
//    S2-covered); E(t) writes x_{t+2} into the DEAD buffer x_lds[p]
//    (x_t was consumed as acc_x at iter t-1). xpre prefetches x_{t+3}.
//
// Mailbox parity-2 safety WITHOUT S1: thread tid polls units 4tid..4tid+3
// — i.e. ALL FOUR WAVES of block tid. So any poll success at tag t+1
// implies every wave of every block passed publish(t+1), hence (program
// order) passed its poll(t) = consumed parity-p tags t. Overwrites of a
// parity slot (at t+2) therefore always follow global consumption (at t).
// Tags monotonic; poll uses >=. Workspace: 8*2*1024 u64 = 128 KB, zeroed.
//
// out rows 0..4094: rotating block (t & 255) writes the full coalesced row
// from poll registers. Row 4095 + h_T + c_T: lane 0 of each wave writes its
// unit at the final step.
// ---------------------------------------------------------------------------
__global__ __launch_bounds__(256, 1) void lstm_fused(
    const float* __restrict__ x,    // [4096,1024]
    const float* __restrict__ W,    // [1024,4096]
    const float* __restrict__ U,    // [1024,4096]
    const float* __restrict__ bias, // [4096]
    float* __restrict__ out,        // [4096*1024 + 1024 + 1024]
    unsigned long long* __restrict__ pairs) // [8][2][1024] {f32,u32}, zeroed
{
    const int tid  = threadIdx.x;
    const int b    = blockIdx.x;
    const int w    = tid >> 6;      // wave index = unit sub-index
    const int l    = tid & 63;
    const int g    = l & 3;         // gate index (i,f,g,o)
    const int seg  = l >> 2;        // h-segment [64*seg, 64*seg+64)
    const int col  = g * 1024 + b * 4 + w;
    const int unit = b * 4 + w;

    __shared__ __align__(16) float h_lds[2][16 * 68];  // h[k] at [par][ (k>>6)*68 + (k&63) ]
    __shared__ __align__(16) float x_lds[2][16 * 68];
    __shared__ __align__(16) float bias_l[16];         // [g*4 + u]

    float Ureg[64], Wreg[64];
    #pragma unroll
    for (int i = 0; i < 64; ++i) {
        const size_t r = (size_t)(seg * 64 + i) * 4096 + col;
        Ureg[i] = U[r];
        Wreg[i] = W[r];
    }
    if (tid < 16) bias_l[tid] = bias[(tid >> 2) * 1024 + b * 4 + (tid & 3)];

    for (int i = tid; i < 2 * 16 * 68; i += 256) ((float*)h_lds)[i] = 0.0f; // h0 = 0
    const int xofs = (tid >> 4) * 68 + (tid & 15) * 4;  // slot of elems [4tid,4tid+4)
    *(f32x4*)&x_lds[0][xofs] = *(const f32x4*)(x + (size_t)tid * 4);          // x_0
    *(f32x4*)&x_lds[1][xofs] = *(const f32x4*)(x + 1024 + (size_t)tid * 4);   // x_1
    f32x4 xpre = *(const f32x4*)(x + 2048 + (size_t)tid * 4);                 // x_2
    __syncthreads();

    const int hbase = seg * 68;

    // prologue: acc_x = W.x_0 partials (4 independent FMA chains)
    float acc_x;
    {
        float b0 = 0.f, b1 = 0.f, b2 = 0.f, b3 = 0.f;
        #pragma unroll
        for (int i = 0; i < 16; ++i) {
            f32x4 x4 = *(const f32x4*)&x_lds[0][hbase + 4 * i];
            b0 += x4.x * Wreg[4*i];   b1 += x4.y * Wreg[4*i+1];
            b2 += x4.z * Wreg[4*i+2]; b3 += x4.w * Wreg[4*i+3];
        }
        acc_x = (b0 + b1) + (b2 + b3);
    }

    float c_reg = 0.0f;   // cell state of unit (b*4+w), replicated on all lanes

    for (int t = 0; t < T_STEPS; ++t) {
        const int p   = t & 1;
        const int nxt = (t + 1) & 1;

        // A: acc = W.x_t (precomputed) + U.h_t partial
        float acc;
        {
            float a0 = 0.f, a1 = 0.f, a2 = 0.f, a3 = 0.f;
            #pragma unroll
            for (int i = 0; i < 16; ++i) {
                f32x4 h4 = *(const f32x4*)&h_lds[p][hbase + 4 * i];
                a0 += h4.x * Ureg[4*i];   a1 += h4.y * Ureg[4*i+1];
                a2 += h4.z * Ureg[4*i+2]; a3 += h4.w * Ureg[4*i+3];
            }
            acc = acc_x + ((a0 + a1) + (a2 + a3));
        }

        // B: intra-wave reduce over the 16 segs (lanes sharing l&3)
        acc += __shfl_xor(acc, 4);
        acc += __shfl_xor(acc, 8);
        acc += __shfl_xor(acc, 16);
        acc += __shfl_xor(acc, 32);
        // lanes l ≡ g (mod 4) now hold the full sum for gate g

        // C: gates (all 64 lanes, redundant — keeps c_reg wave-replicated)
        const float gi = __shfl(acc, 0) + bias_l[0 + w];
        const float gf = __shfl(acc, 1) + bias_l[4 + w];
        const float gg = __shfl(acc, 2) + bias_l[8 + w];
        const float go = __shfl(acc, 3) + bias_l[12 + w];
        const float iv = 1.0f / (1.0f + __expf(-gi));
        const float fv = 1.0f / (1.0f + __expf(-gf));
        const float tg = 1.0f - 2.0f / (1.0f + __expf(2.0f * gg));
        const float ov = 1.0f / (1.0f + __expf(-go));
        const float cn = fv * c_reg + iv * tg;
        c_reg = cn;
        const float hn = ov * (1.0f - 2.0f / (1.0f + __expf(2.0f * cn)));

        if (t == T_STEPS - 1) {
            if (l == 0) {
                out[(size_t)t * HID + unit] = hn;                 // row 4095
                out[(size_t)T_STEPS * HID + unit] = hn;           // h_T
                out[(size_t)T_STEPS * HID + HID + unit] = cn;     // c_T
            }
            break;
        }

        // D: publish — lane r (r<8) stores unit's pair into replica r
        if (l < NREP) {
            u32x2 pr;
            pr.x = f2u(hn);
            pr.y = (unsigned int)(t + 1);
            unsigned long long* pp = pairs + (size_t)l * 2048
                                   + (size_t)p * 1024 + unit;
            asm volatile("global_store_dwordx2 %0, %1, off sc0 sc1"
                         :: "v"(pp), "v"(pr) : "memory");
        }

        // E: rotate x: write x_{t+2} into dead buffer x_lds[p]; prefetch x_{t+3}
        *(f32x4*)&x_lds[p][xofs] = xpre;
        {
            const int tp3 = (t + 3 < T_STEPS) ? (t + 3) : (T_STEPS - 1);
            xpre = *(const f32x4*)(x + (size_t)tp3 * 1024 + tid * 4);
        }

        // F: acc_x = W.x_{t+1} (overlaps publish flight; reads x_lds[nxt],
        //    staged at E(t-1) and S2-covered)
        {
            float b0 = 0.f, b1 = 0.f, b2 = 0.f, b3 = 0.f;
            #pragma unroll
            for (int i = 0; i < 16; ++i) {
                f32x4 x4 = *(const f32x4*)&x_lds[nxt][hbase + 4 * i];
                b0 += x4.x * Wreg[4*i];   b1 += x4.y * Wreg[4*i+1];
                b2 += x4.z * Wreg[4*i+2]; b3 += x4.w * Wreg[4*i+3];
            }
            acc_x = (b0 + b1) + (b2 + b3);
        }

        // G: poll own 4 pairs (units 4tid..4tid+3) from replica (b & 7).
        //    ONE asm block per round; nothing in flight at exit.
        f32x4 hv4;
        {
            const unsigned int want = (unsigned int)(t + 1);
            const unsigned long long* pp = pairs + (size_t)(b & 7) * 2048
                                         + (size_t)p * 1024 + tid * 4;
            u32x4 q0, q1;
            for (;;) {
                asm volatile("global_load_dwordx4 %0, %2, off sc0 sc1\n\t"
                             "global_load_dwordx4 %1, %3, off sc0 sc1\n\t"
                             "s_waitcnt vmcnt(0)"
                             : "=&v"(q0), "=&v"(q1)
                             : "v"(pp), "v"(pp + 2) : "memory");
                if (q0.y >= want && q0.w >= want && q1.y >= want && q1.w >= want)
                    break;
            }
            hv4.x = u2f(q0.x); hv4.y = u2f(q0.z);
            hv4.z = u2f(q1.x); hv4.w = u2f(q1.z);
        }

        // H: rotating writer emits coalesced out row t; stage h_{t+1}
        if (b == (t & 255))
            *(f32x4*)(out + (size_t)t * HID + tid * 4) = hv4;
        *(f32x4*)&h_lds[nxt][xofs] = hv4;

        __syncthreads();   // [S2] h_lds[nxt] + x_lds[p] staged (ONLY barrier)
    }
}

extern "C" void kernel_launch(void* const* d_in, const int* in_sizes, int n_in,
                              void* d_out, int out_size, void* d_ws, size_t ws_size,
                              hipStream_t stream) {
    const float* x    = (const float*)d_in[0];
    const float* W    = (const float*)d_in[1];
    const float* U    = (const float*)d_in[2];
    const float* bias = (const float*)d_in[3];
    float* out = (float*)d_out;

    // Workspace: pairs[8][2][1024] x 8 B = 128 KB @ +0 (zeroed: tag fields
    // must start below 1; re-poisoned 0xAA would read as huge tags).
    unsigned long long* pairs = (unsigned long long*)d_ws;

    hipMemsetAsync(pairs, 0, (size_t)NREP * 2 * 1024 * sizeof(unsigned long long), stream);
    lstm_fused<<<NBLK, 256, 0, stream>>>(x, W, U, bias, out, pairs);
}